// Round 5
// baseline (777.571 us; speedup 1.0000x reference)
//
#include <hip/hip_runtime.h>
#include <stdint.h>

// MST on 128x256 grid, B=4, Boruvka with (weight, eid) total order.
// k_keys: full-grid weight kernel (bit-exact seq accumulation, no FMA).
// k_mst4: 4 blocks (one per batch), par/lab in LDS (u16), best[] in global
// u64 (atomicMin), edge-centric winner hooking. This revision: ILP-staged
// chunked loops (8 independent loads per stage, fully unrolled) replacing
// the serial ffs-while loops; round-0 specialization (identity labels);
// winner check reads only low32 of best.

#define HH 128
#define WW 256
#define NN (HH*WW)          // 32768 = 2^15
#define RE ((HH-1)*WW)      // 32512
#define EE (RE + HH*(WW-1)) // 65152
#define CH 64
#define ROUNDS 15           // components at least halve per round; 2^15 = N
#define EPAD 65536

typedef unsigned long long u64;
typedef unsigned int u32;
typedef unsigned short u16;

__device__ __forceinline__ void edge_uv(int e, int& u, int& v) {
    if (e < RE) { u = e; v = e + WW; }          // row edge (i,j)-(i+1,j)
    else {                                      // col edge (i,j)-(i,j+1)
        int ec = e - RE;
        int i = ec / (WW - 1);
        int j = ec - i * (WW - 1);
        u = i * WW + j; v = u + 1;
    }
}

// weights for batches {b0, b0+2} per thread; also inits best = ~0
__global__ __launch_bounds__(256) void k_keys(const float* __restrict__ g,
                                              u32* __restrict__ keyw,
                                              u64* __restrict__ best) {
    int t = blockIdx.x * blockDim.x + threadIdx.x;   // 0..131071 == B*N
    best[t] = ~0ull;
    int e0 = t & (EPAD - 1);
    int b0 = t >> 16;                                // 0 or 1
    if (e0 >= EE) return;
    int u, v; edge_uv(e0, u, v);
    const float* gb0 = g + (size_t)b0 * CH * NN;
    const float* gb1 = gb0 + (size_t)2 * CH * NN;
    float a0 = 0.f, a1 = 0.f;
    #pragma unroll 8
    for (int c = 0; c < CH; ++c) {
        float x0 = gb0[(size_t)c * NN + u] - gb0[(size_t)c * NN + v];
        float x1 = gb1[(size_t)c * NN + u] - gb1[(size_t)c * NN + v];
        a0 = __fadd_rn(a0, __fmul_rn(x0, x0));       // forbid fma contraction
        a1 = __fadd_rn(a1, __fmul_rn(x1, x1));
    }
    keyw[(b0 << 16) | e0] = __float_as_uint(sqrtf(a0));
    keyw[((b0 + 2) << 16) | e0] = __float_as_uint(sqrtf(a1));
}

__global__ __launch_bounds__(1024) void k_mst4(const u32* __restrict__ keyw,
                                               u64* __restrict__ best,
                                               int* __restrict__ out) {
    __shared__ u16 par[NN];          // 64 KB
    __shared__ u16 lab[NN];          // 64 KB
    __shared__ u32 selw[EPAD / 32];  // 8 KB edge bitmask
    __shared__ int wsum[32];
    __shared__ int sflag[2];

    const int b = (int)blockIdx.x;
    const int tid = (int)threadIdx.x;
    const u32* kb = keyw + (b << 16);
    u64* bb = best + (b << 15);
    const u32* bblo = (const u32*)bb;           // low word of entry n at 2n

    for (int k = tid; k < NN; k += 1024) { par[k] = (u16)k; lab[k] = (u16)k; }
    for (int k = tid; k < EPAD / 32; k += 1024) selw[k] = 0u;
    if (tid == 0) { sflag[0] = 0; sflag[1] = 0; }
    __syncthreads();

    // thread's edge k-bit <-> e = (k<<10)+tid ; k=63 invalid for tid>=640
    u64 dead = (tid >= (EE - 63 * 1024)) ? (1ull << 63) : 0ull;

    // ======== round 0 (identity labels: roots are the endpoints) ========
    for (int c = 0; c < 8; ++c) {
        u32 alive = (u32)((~dead) >> (c * 8)) & 0xFFu;
        u32 kreg[8];
        #pragma unroll
        for (int i = 0; i < 8; ++i) if (alive & (1u << i))
            kreg[i] = kb[((c * 8 + i) << 10) + tid];
        #pragma unroll
        for (int i = 0; i < 8; ++i) if (alive & (1u << i)) {
            int e = ((c * 8 + i) << 10) + tid;
            int u, v; edge_uv(e, u, v);
            u64 key = ((u64)kreg[i] << 32) | (u32)e;
            atomicMin(bb + u, key);
            atomicMin(bb + v, key);
        }
    }
    __syncthreads();                              // drains atomics
    for (int c = 0; c < 8; ++c) {
        u32 am = (u32)((~dead) >> (c * 8)) & 0xFFu;
        u32 blu[8], blv[8];
        #pragma unroll
        for (int i = 0; i < 8; ++i) if (am & (1u << i)) {
            int e = ((c * 8 + i) << 10) + tid;
            int u, v; edge_uv(e, u, v);
            blu[i] = __hip_atomic_load(bblo + 2 * u, __ATOMIC_RELAXED, __HIP_MEMORY_SCOPE_AGENT);
            blv[i] = __hip_atomic_load(bblo + 2 * v, __ATOMIC_RELAXED, __HIP_MEMORY_SCOPE_AGENT);
        }
        #pragma unroll
        for (int i = 0; i < 8; ++i) if (am & (1u << i)) {
            int e = ((c * 8 + i) << 10) + tid;
            int u, v; edge_uv(e, u, v);
            bool wU = (blu[i] == (u32)e);
            bool wV = (blv[i] == (u32)e);
            if (wU | wV) {
                atomicOr(&selw[e >> 5], 1u << (e & 31));
                if (wU & wV) {                    // mutual min: max hooks to min
                    int mn = u < v ? u : v, mx = u < v ? v : u;
                    par[mx] = (u16)mn;
                    __hip_atomic_store(bb + u, ~0ull, __ATOMIC_RELAXED, __HIP_MEMORY_SCOPE_AGENT);
                    __hip_atomic_store(bb + v, ~0ull, __ATOMIC_RELAXED, __HIP_MEMORY_SCOPE_AGENT);
                } else if (wU) {
                    par[u] = (u16)v;
                    __hip_atomic_store(bb + u, ~0ull, __ATOMIC_RELAXED, __HIP_MEMORY_SCOPE_AGENT);
                } else {
                    par[v] = (u16)u;
                    __hip_atomic_store(bb + v, ~0ull, __ATOMIC_RELAXED, __HIP_MEMORY_SCOPE_AGENT);
                }
            }
        }
    }
    __syncthreads();

    // ======== generic rounds ========
    for (int r = 1; r < ROUNDS; ++r) {
        // ---- phase A: staged root-chase + compress + scatter atomicMin
        u64 act = 0;
        for (int c = 0; c < 8; ++c) {
            u32 alive = (u32)((~dead) >> (c * 8)) & 0xFFu;
            if (!alive) continue;
            u32 ru[8], rv[8], kreg[8], p[8];
            #pragma unroll
            for (int i = 0; i < 8; ++i) if (alive & (1u << i)) {
                int e = ((c * 8 + i) << 10) + tid;
                int u, v; edge_uv(e, u, v);
                ru[i] = lab[u]; rv[i] = lab[v];
                kreg[i] = kb[e];
            }
            #pragma unroll
            for (int i = 0; i < 8; ++i) if (alive & (1u << i)) p[i] = par[ru[i]];
            #pragma unroll
            for (int i = 0; i < 8; ++i) if (alive & (1u << i)) {
                u32 rr = ru[i], q = p[i];
                while (q != rr) { rr = q; q = par[rr]; }
                ru[i] = rr;
            }
            #pragma unroll
            for (int i = 0; i < 8; ++i) if (alive & (1u << i)) p[i] = par[rv[i]];
            #pragma unroll
            for (int i = 0; i < 8; ++i) if (alive & (1u << i)) {
                u32 rr = rv[i], q = p[i];
                while (q != rr) { rr = q; q = par[rr]; }
                rv[i] = rr;
            }
            #pragma unroll
            for (int i = 0; i < 8; ++i) if (alive & (1u << i)) {
                int k = c * 8 + i;
                int e = (k << 10) + tid;
                int u, v; edge_uv(e, u, v);
                lab[u] = (u16)ru[i]; lab[v] = (u16)rv[i];   // benign races
                if (ru[i] == rv[i]) dead |= 1ull << k;
                else {
                    act |= 1ull << k;
                    u64 key = ((u64)kreg[i] << 32) | (u32)e;
                    atomicMin(bb + ru[i], key);
                    atomicMin(bb + rv[i], key);
                }
            }
        }
        if (act) sflag[r & 1] = 1;               // benign race: same value
        __syncthreads();                          // drains atomics + flag
        if (!sflag[r & 1]) break;                 // uniform
        if (tid == 0) sflag[(r + 1) & 1] = 0;
        // ---- phase B: staged winner check (low32 only) + hook + reset
        for (int c = 0; c < 8; ++c) {
            u32 am = (u32)(act >> (c * 8)) & 0xFFu;
            if (!am) continue;
            u32 ru[8], rv[8], blu[8], blv[8];
            #pragma unroll
            for (int i = 0; i < 8; ++i) if (am & (1u << i)) {
                int e = ((c * 8 + i) << 10) + tid;
                int u, v; edge_uv(e, u, v);
                ru[i] = lab[u]; rv[i] = lab[v];   // exact roots this phase
            }
            #pragma unroll
            for (int i = 0; i < 8; ++i) if (am & (1u << i)) {
                blu[i] = __hip_atomic_load(bblo + 2 * ru[i], __ATOMIC_RELAXED, __HIP_MEMORY_SCOPE_AGENT);
                blv[i] = __hip_atomic_load(bblo + 2 * rv[i], __ATOMIC_RELAXED, __HIP_MEMORY_SCOPE_AGENT);
            }
            #pragma unroll
            for (int i = 0; i < 8; ++i) if (am & (1u << i)) {
                int e = ((c * 8 + i) << 10) + tid;
                bool wU = (blu[i] == (u32)e);     // reset low32=~0 can't match
                bool wV = (blv[i] == (u32)e);
                if (wU | wV) {
                    atomicOr(&selw[e >> 5], 1u << (e & 31));
                    u32 a = ru[i], d2 = rv[i];
                    if (wU & wV) {                // mutual min: max hooks to min
                        u32 mn = a < d2 ? a : d2, mx = a < d2 ? d2 : a;
                        par[mx] = (u16)mn;
                        __hip_atomic_store(bb + a,  ~0ull, __ATOMIC_RELAXED, __HIP_MEMORY_SCOPE_AGENT);
                        __hip_atomic_store(bb + d2, ~0ull, __ATOMIC_RELAXED, __HIP_MEMORY_SCOPE_AGENT);
                    } else if (wU) {
                        par[a] = (u16)d2;
                        __hip_atomic_store(bb + a,  ~0ull, __ATOMIC_RELAXED, __HIP_MEMORY_SCOPE_AGENT);
                    } else {
                        par[d2] = (u16)a;
                        __hip_atomic_store(bb + d2, ~0ull, __ATOMIC_RELAXED, __HIP_MEMORY_SCOPE_AGENT);
                    }
                }
            }
        }
        __syncthreads();
    }

    // ---- in-block stable compaction from LDS bitmask (thread owns 64 eids)
    u32 w0 = selw[tid * 2], w1 = selw[tid * 2 + 1];
    int cnt = __popc(w0) + __popc(w1);
    int lane = tid & 63, wid = tid >> 6;
    int inc = cnt;
    #pragma unroll
    for (int d = 1; d < 64; d <<= 1) {
        int t2 = __shfl_up(inc, d, 64);
        if (lane >= d) inc += t2;
    }
    if (lane == 63) wsum[wid] = inc;
    __syncthreads();
    if (tid < 16) {
        int vv = wsum[tid];
        int inc2 = vv;
        #pragma unroll
        for (int d = 1; d < 16; d <<= 1) {
            int t2 = __shfl_up(inc2, d, 16);
            if (tid >= d) inc2 += t2;
        }
        wsum[tid] = inc2 - vv;                    // exclusive wave base
    }
    __syncthreads();
    int pos = wsum[wid] + inc - cnt;
    int* ob = out + (size_t)b * (NN - 1) * 2;
    u64 bits = ((u64)w1 << 32) | (u64)w0;
    while (bits) {
        int bi = __ffsll((long long)bits) - 1;
        bits &= bits - 1;
        int e = (tid << 6) + bi;
        int u, v; edge_uv(e, u, v);
        ob[(size_t)pos * 2] = u;
        ob[(size_t)pos * 2 + 1] = v;
        ++pos;
    }
}

extern "C" void kernel_launch(void* const* d_in, const int* in_sizes, int n_in,
                              void* d_out, int out_size, void* d_ws, size_t ws_size,
                              hipStream_t stream) {
    const float* g = (const float*)d_in[0];
    int* out = (int*)d_out;
    char* ws = (char*)d_ws;

    u64* best = (u64*)ws;                            // B*N*8 = 1 MB
    u32* keyw = (u32*)(ws + (size_t)4 * NN * 8);     // B*EPAD*4 = 1 MB

    k_keys<<<512, 256, 0, stream>>>(g, keyw, best);
    k_mst4<<<4, 1024, 0, stream>>>(keyw, best, out);
}

// Round 6
// 688.370 us; speedup vs baseline: 1.1296x; 1.1296x over previous
//
#include <hip/hip_runtime.h>
#include <stdint.h>

// MST on 128x256 grid, B=4, Boruvka with (weight, eid) total order.
// k_keys: full-grid weight kernel (bit-exact seq accumulation, no FMA).
// k_mst4: 4 blocks (one per batch), par/lab in LDS (u16), best[] in global.
// This revision: ALL best[] traffic demoted from agent scope (memory-side
// atomics, ~900cy, HBM write-through) to WORKGROUP scope (own-XCD L2) —
// best[b] is only ever touched by block b, so wg scope is sufficient.
// Reads of best are atomic-RMW (fetch_or 0) so they execute at L2 and can
// never hit a stale L1 line.

#define HH 128
#define WW 256
#define NN (HH*WW)          // 32768 = 2^15
#define RE ((HH-1)*WW)      // 32512
#define EE (RE + HH*(WW-1)) // 65152
#define CH 64
#define ROUNDS 15           // components at least halve per round; 2^15 = N
#define EPAD 65536

typedef unsigned long long u64;
typedef unsigned int u32;
typedef unsigned short u16;

#define BMIN(p, k)  __hip_atomic_fetch_min((p), (k), __ATOMIC_RELAXED, __HIP_MEMORY_SCOPE_WORKGROUP)
#define BGET32(p)   __hip_atomic_fetch_or((p), 0u, __ATOMIC_RELAXED, __HIP_MEMORY_SCOPE_WORKGROUP)
#define BRST(p)     __hip_atomic_store((p), ~0ull, __ATOMIC_RELAXED, __HIP_MEMORY_SCOPE_WORKGROUP)

__device__ __forceinline__ void edge_uv(int e, int& u, int& v) {
    if (e < RE) { u = e; v = e + WW; }          // row edge (i,j)-(i+1,j)
    else {                                      // col edge (i,j)-(i,j+1)
        int ec = e - RE;
        int i = ec / (WW - 1);
        int j = ec - i * (WW - 1);
        u = i * WW + j; v = u + 1;
    }
}

// weights for batches {b0, b0+2} per thread; also inits best = ~0
__global__ __launch_bounds__(256) void k_keys(const float* __restrict__ g,
                                              u32* __restrict__ keyw,
                                              u64* __restrict__ best) {
    int t = blockIdx.x * blockDim.x + threadIdx.x;   // 0..131071 == B*N
    best[t] = ~0ull;
    int e0 = t & (EPAD - 1);
    int b0 = t >> 16;                                // 0 or 1
    if (e0 >= EE) return;
    int u, v; edge_uv(e0, u, v);
    const float* gb0 = g + (size_t)b0 * CH * NN;
    const float* gb1 = gb0 + (size_t)2 * CH * NN;
    float a0 = 0.f, a1 = 0.f;
    #pragma unroll 8
    for (int c = 0; c < CH; ++c) {
        float x0 = gb0[(size_t)c * NN + u] - gb0[(size_t)c * NN + v];
        float x1 = gb1[(size_t)c * NN + u] - gb1[(size_t)c * NN + v];
        a0 = __fadd_rn(a0, __fmul_rn(x0, x0));       // forbid fma contraction
        a1 = __fadd_rn(a1, __fmul_rn(x1, x1));
    }
    keyw[(b0 << 16) | e0] = __float_as_uint(sqrtf(a0));
    keyw[((b0 + 2) << 16) | e0] = __float_as_uint(sqrtf(a1));
}

__global__ __launch_bounds__(1024) void k_mst4(const u32* __restrict__ keyw,
                                               u64* __restrict__ best,
                                               int* __restrict__ out) {
    __shared__ u16 par[NN];          // 64 KB
    __shared__ u16 lab[NN];          // 64 KB
    __shared__ u32 selw[EPAD / 32];  // 8 KB edge bitmask
    __shared__ int wsum[32];
    __shared__ int sflag[2];

    const int b = (int)blockIdx.x;
    const int tid = (int)threadIdx.x;
    const u32* kb = keyw + (b << 16);
    u64* bb = best + (b << 15);
    u32* bblo = (u32*)bb;                       // low word of entry n at 2n

    for (int k = tid; k < NN; k += 1024) { par[k] = (u16)k; lab[k] = (u16)k; }
    for (int k = tid; k < EPAD / 32; k += 1024) selw[k] = 0u;
    if (tid == 0) { sflag[0] = 0; sflag[1] = 0; }
    __syncthreads();

    // thread's edge k-bit <-> e = (k<<10)+tid ; k=63 invalid for tid>=640
    u64 dead = (tid >= (EE - 63 * 1024)) ? (1ull << 63) : 0ull;

    // ======== round 0 (identity labels: roots are the endpoints) ========
    for (int c = 0; c < 8; ++c) {
        u32 alive = (u32)((~dead) >> (c * 8)) & 0xFFu;
        u32 kreg[8];
        #pragma unroll
        for (int i = 0; i < 8; ++i) if (alive & (1u << i))
            kreg[i] = kb[((c * 8 + i) << 10) + tid];
        #pragma unroll
        for (int i = 0; i < 8; ++i) if (alive & (1u << i)) {
            int e = ((c * 8 + i) << 10) + tid;
            int u, v; edge_uv(e, u, v);
            u64 key = ((u64)kreg[i] << 32) | (u32)e;
            BMIN(bb + u, key);
            BMIN(bb + v, key);
        }
    }
    __syncthreads();                              // drains atomics
    for (int c = 0; c < 8; ++c) {
        u32 am = (u32)((~dead) >> (c * 8)) & 0xFFu;
        u32 blu[8], blv[8];
        #pragma unroll
        for (int i = 0; i < 8; ++i) if (am & (1u << i)) {
            int e = ((c * 8 + i) << 10) + tid;
            int u, v; edge_uv(e, u, v);
            blu[i] = BGET32(bblo + 2 * u);
            blv[i] = BGET32(bblo + 2 * v);
        }
        #pragma unroll
        for (int i = 0; i < 8; ++i) if (am & (1u << i)) {
            int e = ((c * 8 + i) << 10) + tid;
            int u, v; edge_uv(e, u, v);
            bool wU = (blu[i] == (u32)e);
            bool wV = (blv[i] == (u32)e);
            if (wU | wV) {
                atomicOr(&selw[e >> 5], 1u << (e & 31));
                if (wU & wV) {                    // mutual min: max hooks to min
                    int mn = u < v ? u : v, mx = u < v ? v : u;
                    par[mx] = (u16)mn;
                    BRST(bb + u);
                    BRST(bb + v);
                } else if (wU) {
                    par[u] = (u16)v;
                    BRST(bb + u);
                } else {
                    par[v] = (u16)u;
                    BRST(bb + v);
                }
            }
        }
    }
    __syncthreads();

    // ======== generic rounds ========
    for (int r = 1; r < ROUNDS; ++r) {
        // ---- phase A: staged root-chase + compress + scatter atomicMin
        u64 act = 0;
        for (int c = 0; c < 8; ++c) {
            u32 alive = (u32)((~dead) >> (c * 8)) & 0xFFu;
            if (!alive) continue;
            u32 ru[8], rv[8], kreg[8], p[8];
            #pragma unroll
            for (int i = 0; i < 8; ++i) if (alive & (1u << i)) {
                int e = ((c * 8 + i) << 10) + tid;
                int u, v; edge_uv(e, u, v);
                ru[i] = lab[u]; rv[i] = lab[v];
                kreg[i] = kb[e];
            }
            #pragma unroll
            for (int i = 0; i < 8; ++i) if (alive & (1u << i)) p[i] = par[ru[i]];
            #pragma unroll
            for (int i = 0; i < 8; ++i) if (alive & (1u << i)) {
                u32 rr = ru[i], q = p[i];
                while (q != rr) { rr = q; q = par[rr]; }
                ru[i] = rr;
            }
            #pragma unroll
            for (int i = 0; i < 8; ++i) if (alive & (1u << i)) p[i] = par[rv[i]];
            #pragma unroll
            for (int i = 0; i < 8; ++i) if (alive & (1u << i)) {
                u32 rr = rv[i], q = p[i];
                while (q != rr) { rr = q; q = par[rr]; }
                rv[i] = rr;
            }
            #pragma unroll
            for (int i = 0; i < 8; ++i) if (alive & (1u << i)) {
                int k = c * 8 + i;
                int e = (k << 10) + tid;
                int u, v; edge_uv(e, u, v);
                lab[u] = (u16)ru[i]; lab[v] = (u16)rv[i];   // benign races
                if (ru[i] == rv[i]) dead |= 1ull << k;
                else {
                    act |= 1ull << k;
                    u64 key = ((u64)kreg[i] << 32) | (u32)e;
                    BMIN(bb + ru[i], key);
                    BMIN(bb + rv[i], key);
                }
            }
        }
        if (act) sflag[r & 1] = 1;               // benign race: same value
        __syncthreads();                          // drains atomics + flag
        if (!sflag[r & 1]) break;                 // uniform
        if (tid == 0) sflag[(r + 1) & 1] = 0;
        // ---- phase B: staged winner check (low32 only) + hook + reset
        for (int c = 0; c < 8; ++c) {
            u32 am = (u32)(act >> (c * 8)) & 0xFFu;
            if (!am) continue;
            u32 ru[8], rv[8], blu[8], blv[8];
            #pragma unroll
            for (int i = 0; i < 8; ++i) if (am & (1u << i)) {
                int e = ((c * 8 + i) << 10) + tid;
                int u, v; edge_uv(e, u, v);
                ru[i] = lab[u]; rv[i] = lab[v];   // exact roots this phase
            }
            #pragma unroll
            for (int i = 0; i < 8; ++i) if (am & (1u << i)) {
                blu[i] = BGET32(bblo + 2 * ru[i]);
                blv[i] = BGET32(bblo + 2 * rv[i]);
            }
            #pragma unroll
            for (int i = 0; i < 8; ++i) if (am & (1u << i)) {
                int e = ((c * 8 + i) << 10) + tid;
                bool wU = (blu[i] == (u32)e);     // reset low32=~0 can't match
                bool wV = (blv[i] == (u32)e);
                if (wU | wV) {
                    atomicOr(&selw[e >> 5], 1u << (e & 31));
                    u32 a = ru[i], d2 = rv[i];
                    if (wU & wV) {                // mutual min: max hooks to min
                        u32 mn = a < d2 ? a : d2, mx = a < d2 ? d2 : a;
                        par[mx] = (u16)mn;
                        BRST(bb + a);
                        BRST(bb + d2);
                    } else if (wU) {
                        par[a] = (u16)d2;
                        BRST(bb + a);
                    } else {
                        par[d2] = (u16)a;
                        BRST(bb + d2);
                    }
                }
            }
        }
        __syncthreads();
    }

    // ---- in-block stable compaction from LDS bitmask (thread owns 64 eids)
    u32 w0 = selw[tid * 2], w1 = selw[tid * 2 + 1];
    int cnt = __popc(w0) + __popc(w1);
    int lane = tid & 63, wid = tid >> 6;
    int inc = cnt;
    #pragma unroll
    for (int d = 1; d < 64; d <<= 1) {
        int t2 = __shfl_up(inc, d, 64);
        if (lane >= d) inc += t2;
    }
    if (lane == 63) wsum[wid] = inc;
    __syncthreads();
    if (tid < 16) {
        int vv = wsum[tid];
        int inc2 = vv;
        #pragma unroll
        for (int d = 1; d < 16; d <<= 1) {
            int t2 = __shfl_up(inc2, d, 16);
            if (tid >= d) inc2 += t2;
        }
        wsum[tid] = inc2 - vv;                    // exclusive wave base
    }
    __syncthreads();
    int pos = wsum[wid] + inc - cnt;
    int* ob = out + (size_t)b * (NN - 1) * 2;
    u64 bits = ((u64)w1 << 32) | (u64)w0;
    while (bits) {
        int bi = __ffsll((long long)bits) - 1;
        bits &= bits - 1;
        int e = (tid << 6) + bi;
        int u, v; edge_uv(e, u, v);
        ob[(size_t)pos * 2] = u;
        ob[(size_t)pos * 2 + 1] = v;
        ++pos;
    }
}

extern "C" void kernel_launch(void* const* d_in, const int* in_sizes, int n_in,
                              void* d_out, int out_size, void* d_ws, size_t ws_size,
                              hipStream_t stream) {
    const float* g = (const float*)d_in[0];
    int* out = (int*)d_out;
    char* ws = (char*)d_ws;

    u64* best = (u64*)ws;                            // B*N*8 = 1 MB
    u32* keyw = (u32*)(ws + (size_t)4 * NN * 8);     // B*EPAD*4 = 1 MB

    k_keys<<<512, 256, 0, stream>>>(g, keyw, best);
    k_mst4<<<4, 1024, 0, stream>>>(keyw, best, out);
}

// Round 7
// 397.683 us; speedup vs baseline: 1.9553x; 1.7309x over previous
//
#include <hip/hip_runtime.h>
#include <stdint.h>

// MST on 128x256 grid, B=4, Boruvka with (weight, eid) total order.
// k_keys: weights, bit-exact seq accumulation (no FMA).
// k_mst4: 4 blocks (one per batch). ZERO global atomics:
//   A[32768] u32 in LDS serves as bestW -> bestE -> hooks each round.
//   lab (u16/node) in global, own-L1 cached (workgroup-private).
//   Round 0: per-node min over <=4 incident edges, no atomics at all.
//   Rounds >=1: two-pass LDS atomicMin (w then eid) == lexicographic argmin.

#define HH 128
#define WW 256
#define NN (HH*WW)          // 32768 = 2^15
#define RE ((HH-1)*WW)      // 32512
#define EE (RE + HH*(WW-1)) // 65152
#define CH 64
#define ROUNDS 15           // components at least halve per round; 2^15 = N
#define EPAD 65536

typedef unsigned long long u64;
typedef unsigned int u32;
typedef unsigned short u16;

__device__ __forceinline__ void edge_uv(int e, int& u, int& v) {
    if (e < RE) { u = e; v = e + WW; }          // row edge (i,j)-(i+1,j)
    else {                                      // col edge (i,j)-(i,j+1)
        int ec = e - RE;
        int i = ec / (WW - 1);
        int j = ec - i * (WW - 1);
        u = i * WW + j; v = u + 1;
    }
}

// weights for batches {b0, b0+2} per thread
__global__ __launch_bounds__(256) void k_keys(const float* __restrict__ g,
                                              u32* __restrict__ keyw) {
    int t = blockIdx.x * blockDim.x + threadIdx.x;   // 0..131071
    int e0 = t & (EPAD - 1);
    int b0 = t >> 16;                                // 0 or 1
    if (e0 >= EE) return;
    int u, v; edge_uv(e0, u, v);
    const float* gb0 = g + (size_t)b0 * CH * NN;
    const float* gb1 = gb0 + (size_t)2 * CH * NN;
    float a0 = 0.f, a1 = 0.f;
    #pragma unroll 8
    for (int c = 0; c < CH; ++c) {
        float x0 = gb0[(size_t)c * NN + u] - gb0[(size_t)c * NN + v];
        float x1 = gb1[(size_t)c * NN + u] - gb1[(size_t)c * NN + v];
        a0 = __fadd_rn(a0, __fmul_rn(x0, x0));       // forbid fma contraction
        a1 = __fadd_rn(a1, __fmul_rn(x1, x1));
    }
    keyw[(b0 << 16) | e0] = __float_as_uint(sqrtf(a0));
    keyw[((b0 + 2) << 16) | e0] = __float_as_uint(sqrtf(a1));
}

__global__ __launch_bounds__(1024) void k_mst4(const u32* __restrict__ keyw,
                                               u16* __restrict__ lab,
                                               int* __restrict__ out) {
    __shared__ u32 A[NN];            // 128 KB: bestW / bestE / hooks
    __shared__ u32 selw[EPAD / 32];  // 8 KB edge bitmask
    __shared__ int wsum[32];
    __shared__ int sflag[2];

    const int b = (int)blockIdx.x;
    const int tid = (int)threadIdx.x;
    const u32* kb = keyw + (b << 16);
    u16* glab = lab + ((size_t)b << 15);

    for (int k = tid; k < EPAD / 32; k += 1024) selw[k] = 0u;
    if (tid == 0) { sflag[0] = 0; sflag[1] = 0; }

    // ======== round 0: per-node argmin over incident edges (no atomics) ====
    for (int n = tid; n < NN; n += 1024) {
        int i = n >> 8, j = n & 255;
        u64 bk = ~0ull;
        if (i > 0)      { int e = n - WW;                u64 kk = ((u64)kb[e] << 32) | (u32)e; bk = kk < bk ? kk : bk; }
        if (i < HH - 1) { int e = n;                     u64 kk = ((u64)kb[e] << 32) | (u32)e; bk = kk < bk ? kk : bk; }
        if (j > 0)      { int e = RE + i * (WW-1) + j-1; u64 kk = ((u64)kb[e] << 32) | (u32)e; bk = kk < bk ? kk : bk; }
        if (j < WW - 1) { int e = RE + i * (WW-1) + j;   u64 kk = ((u64)kb[e] << 32) | (u32)e; bk = kk < bk ? kk : bk; }
        A[n] = (u32)bk;                          // argmin eid
    }
    __syncthreads();
    // mark selected edges; relabel by chasing the implicit hook function
    for (int n = tid; n < NN; n += 1024) {
        int e0 = (int)A[n];
        atomicOr(&selw[e0 >> 5], 1u << (e0 & 31));
        int r = n;
        for (;;) {
            int e = (int)A[r];
            int u, v; edge_uv(e, u, v);
            int o = (u == r) ? v : u;
            if ((int)A[o] == e) { r = (r < o) ? r : o; break; }  // mutual pair
            r = o;
        }
        glab[n] = (u16)r;
    }
    __syncthreads();

    // ======== rounds 1..14 ========
    // thread's edge k-bit <-> e = (k<<10)+tid ; k=63 invalid for tid>=640
    u64 dead = (tid >= (EE - 63 * 1024)) ? (1ull << 63) : 0ull;

    for (int r = 1; r < ROUNDS; ++r) {
        for (int c = tid; c < NN; c += 1024) A[c] = ~0u;   // bestW init
        __syncthreads();
        // ---- phase A: alive classify + bestW (LDS atomics)
        u64 act = 0;
        { u64 m = ~dead;
          while (m) {
            int k = __ffsll((long long)m) - 1; m &= m - 1;
            int e = (k << 10) + tid;
            int u, v; edge_uv(e, u, v);
            u32 cu = glab[u], cv = glab[v];
            if (cu == cv) { dead |= 1ull << k; continue; }
            act |= 1ull << k;
            u32 wk = kb[e];
            atomicMin(&A[cu], wk);
            atomicMin(&A[cv], wk);
          } }
        if (act) sflag[r & 1] = 1;               // benign race: same value
        __syncthreads();
        if (!sflag[r & 1]) break;                // uniform
        if (tid == 0) sflag[(r + 1) & 1] = 0;
        // ---- phase B: weight-match masks
        u64 mu = 0, mv = 0;
        { u64 m = act;
          while (m) {
            int k = __ffsll((long long)m) - 1; m &= m - 1;
            int e = (k << 10) + tid;
            int u, v; edge_uv(e, u, v);
            u32 wk = kb[e];
            if (A[glab[u]] == wk) mu |= 1ull << k;
            if (A[glab[v]] == wk) mv |= 1ull << k;
          } }
        __syncthreads();
        for (int c = tid; c < NN; c += 1024) A[c] = ~0u;   // bestE init
        __syncthreads();
        // ---- phase C: eid-min among weight-matched
        { u64 m = mu | mv;
          while (m) {
            int k = __ffsll((long long)m) - 1; m &= m - 1;
            int e = (k << 10) + tid;
            int u, v; edge_uv(e, u, v);
            if (mu & (1ull << k)) atomicMin(&A[glab[u]], (u32)e);
            if (mv & (1ull << k)) atomicMin(&A[glab[v]], (u32)e);
          } }
        __syncthreads();
        // ---- phase D: unique winner check
        u64 wu = 0, wv = 0;
        { u64 m = mu | mv;
          while (m) {
            int k = __ffsll((long long)m) - 1; m &= m - 1;
            int e = (k << 10) + tid;
            int u, v; edge_uv(e, u, v);
            if ((mu & (1ull << k)) && A[glab[u]] == (u32)e) wu |= 1ull << k;
            if ((mv & (1ull << k)) && A[glab[v]] == (u32)e) wv |= 1ull << k;
          } }
        __syncthreads();
        // ---- phase D2: self-hooks for untouched comps + winner hooks
        // sweep writes only ~0 entries; winners overwrite bestE entries:
        // disjoint addresses, racing reads see !=~0 either way -> benign.
        for (int c = tid; c < NN; c += 1024) { if (A[c] == ~0u) A[c] = (u32)c; }
        { u64 m = wu | wv;
          while (m) {
            int k = __ffsll((long long)m) - 1; m &= m - 1;
            int e = (k << 10) + tid;
            int u, v; edge_uv(e, u, v);
            u32 cu = glab[u], cv = glab[v];
            atomicOr(&selw[e >> 5], 1u << (e & 31));
            bool BU = (wu >> k) & 1, BV = (wv >> k) & 1;
            if (BU && BV) {                      // mutual min: min id is root
                u32 mn = cu < cv ? cu : cv, mx = cu < cv ? cv : cu;
                A[mx] = mn; A[mn] = mn;
            } else if (BU) A[cu] = cv;
            else           A[cv] = cu;
          } }
        __syncthreads();
        // ---- phase F: relabel all nodes to new roots
        for (int n = tid; n < NN; n += 1024) {
            u32 rr = glab[n];
            u32 x = A[rr];
            while (x != rr) { rr = x; x = A[rr]; }
            glab[n] = (u16)rr;
        }
        __syncthreads();
    }

    // ---- in-block stable compaction from LDS bitmask (thread owns 64 eids)
    u32 w0 = selw[tid * 2], w1 = selw[tid * 2 + 1];
    int cnt = __popc(w0) + __popc(w1);
    int lane = tid & 63, wid = tid >> 6;
    int inc = cnt;
    #pragma unroll
    for (int d = 1; d < 64; d <<= 1) {
        int t2 = __shfl_up(inc, d, 64);
        if (lane >= d) inc += t2;
    }
    if (lane == 63) wsum[wid] = inc;
    __syncthreads();
    if (tid < 16) {
        int vv = wsum[tid];
        int inc2 = vv;
        #pragma unroll
        for (int d = 1; d < 16; d <<= 1) {
            int t2 = __shfl_up(inc2, d, 16);
            if (tid >= d) inc2 += t2;
        }
        wsum[tid] = inc2 - vv;                    // exclusive wave base
    }
    __syncthreads();
    int pos = wsum[wid] + inc - cnt;
    int* ob = out + (size_t)b * (NN - 1) * 2;
    u64 bits = ((u64)w1 << 32) | (u64)w0;
    while (bits) {
        int bi = __ffsll((long long)bits) - 1;
        bits &= bits - 1;
        int e = (tid << 6) + bi;
        int u, v; edge_uv(e, u, v);
        ob[(size_t)pos * 2] = u;
        ob[(size_t)pos * 2 + 1] = v;
        ++pos;
    }
}

extern "C" void kernel_launch(void* const* d_in, const int* in_sizes, int n_in,
                              void* d_out, int out_size, void* d_ws, size_t ws_size,
                              hipStream_t stream) {
    const float* g = (const float*)d_in[0];
    int* out = (int*)d_out;
    char* ws = (char*)d_ws;

    u32* keyw = (u32*)ws;                            // B*EPAD*4 = 1 MB
    u16* lab  = (u16*)(ws + (size_t)4 * EPAD * 4);   // B*N*2 = 256 KB

    k_keys<<<512, 256, 0, stream>>>(g, keyw);
    k_mst4<<<4, 1024, 0, stream>>>(keyw, lab, out);
}

// Round 8
// 300.431 us; speedup vs baseline: 2.5882x; 1.3237x over previous
//
#include <hip/hip_runtime.h>
#include <stdint.h>

// MST on 128x256 grid, B=4, Boruvka with (weight, eid) total order.
// k_keys: weights, bit-exact seq accumulation (no FMA) — verified.
// k_mst4: 4 blocks (one per batch), EVERYTHING in LDS:
//   lab u16[NN] (64KB) + W u64[8192]/u32[16384] overlay (64KB) + sel (8KB).
//   Round 0: per-node argmin via packed 2-bit dirs, no atomics.
//   Round 1: comp space C0<=16384, two-pass u32 LDS atomicMin (w, then eid).
//   Rounds >=2: C<=8192, single-pass u64 LDS atomicMin of (w<<32)|(e+KOFF);
//     KOFF keeps key low-words disjoint from hook/root values => torn-read safe.
//   Hooks written tag-in-place into W (sole-writer = winner, tag bit kills
//   false winner matches). Renumber via wave-aggregated atomicAdd; C==1 ends.

#define HH 128
#define WW 256
#define NN (HH*WW)          // 32768 = 2^15
#define RE ((HH-1)*WW)      // 32512
#define EE (RE + HH*(WW-1)) // 65152
#define CH 64
#define EPAD 65536
#define KOFF 0x10000u
#define TAG32 0x80000000u
#define TAG64 (1ull << 63)

typedef unsigned long long u64;
typedef unsigned int u32;
typedef unsigned short u16;

__device__ __forceinline__ void edge_uv(int e, int& u, int& v) {
    if (e < RE) { u = e; v = e + WW; }          // row edge (i,j)-(i+1,j)
    else {                                      // col edge (i,j)-(i,j+1)
        int ec = e - RE;
        int i = ec / (WW - 1);
        int j = ec - i * (WW - 1);
        u = i * WW + j; v = u + 1;
    }
}

// weights for batches {b0, b0+2} per thread
__global__ __launch_bounds__(256) void k_keys(const float* __restrict__ g,
                                              u32* __restrict__ keyw) {
    int t = blockIdx.x * blockDim.x + threadIdx.x;   // 0..131071
    int e0 = t & (EPAD - 1);
    int b0 = t >> 16;                                // 0 or 1
    if (e0 >= EE) return;
    int u, v; edge_uv(e0, u, v);
    const float* gb0 = g + (size_t)b0 * CH * NN;
    const float* gb1 = gb0 + (size_t)2 * CH * NN;
    float a0 = 0.f, a1 = 0.f;
    #pragma unroll 8
    for (int c = 0; c < CH; ++c) {
        float x0 = gb0[(size_t)c * NN + u] - gb0[(size_t)c * NN + v];
        float x1 = gb1[(size_t)c * NN + u] - gb1[(size_t)c * NN + v];
        a0 = __fadd_rn(a0, __fmul_rn(x0, x0));       // forbid fma contraction
        a1 = __fadd_rn(a1, __fmul_rn(x1, x1));
    }
    keyw[(b0 << 16) | e0] = __float_as_uint(sqrtf(a0));
    keyw[((b0 + 2) << 16) | e0] = __float_as_uint(sqrtf(a1));
}

__global__ __launch_bounds__(1024) void k_mst4(const u32* __restrict__ keyw,
                                               int* __restrict__ out) {
    __shared__ u16 lab[NN];          // 64 KB node -> compact comp id
    __shared__ u64 Wbuf[8192];       // 64 KB: dirs / nid map / bestW / bestE / keys / hooks
    __shared__ u32 selw[EPAD / 32];  // 8 KB edge bitmask
    __shared__ int wsum[32];
    __shared__ int cntc;

    u32* W32 = (u32*)Wbuf;           // [0, 16384)
    u16* W16 = (u16*)Wbuf;           // [0, 32768)
    u32* D0  = (u32*)Wbuf;           // [0, 2048) 2-bit dirs, 16 nodes/word

    const int b = (int)blockIdx.x;
    const int tid = (int)threadIdx.x;
    const u32* kb = keyw + (b << 16);
    const int lane = tid & 63;

    for (int k = tid; k < EPAD / 32; k += 1024) selw[k] = 0u;
    if (tid == 0) cntc = 0;
    __syncthreads();

    // ======== round 0, step 1: per-node argmin dir (no atomics on W) ======
    {
        int base = tid * 32, i = base >> 8, j0 = base & 255;
        u32 w0 = 0, w1 = 0;
        for (int ii = 0; ii < 32; ++ii) {
            int n = base + ii, j = j0 + ii;
            u64 bk = ~0ull; u32 bd = 0; int be = 0;
            if (i > 0)      { int e = n - WW;                 u64 kk = ((u64)kb[e] << 32) | (u32)e; if (kk < bk) { bk = kk; bd = 0; be = e; } }
            if (i < HH - 1) { int e = n;                      u64 kk = ((u64)kb[e] << 32) | (u32)e; if (kk < bk) { bk = kk; bd = 1; be = e; } }
            if (j > 0)      { int e = RE + i * (WW-1) + j-1;  u64 kk = ((u64)kb[e] << 32) | (u32)e; if (kk < bk) { bk = kk; bd = 2; be = e; } }
            if (j < WW - 1) { int e = RE + i * (WW-1) + j;    u64 kk = ((u64)kb[e] << 32) | (u32)e; if (kk < bk) { bk = kk; bd = 3; be = e; } }
            atomicOr(&selw[be >> 5], 1u << (be & 31));
            if (ii < 16) w0 |= bd << (2 * ii); else w1 |= bd << (2 * (ii - 16));
        }
        D0[2 * tid] = w0; D0[2 * tid + 1] = w1;
    }
    __syncthreads();
    // ---- step 2: chase dir-graph to mutual pair; lab[n] = node-space root
    for (int n = tid; n < NN; n += 1024) {
        int cur = n;
        int d = (int)((D0[cur >> 4] >> ((cur & 15) * 2)) & 3u);
        for (;;) {
            int i2 = cur >> 8, j2 = cur & 255;
            int e = (d == 0) ? cur - WW : (d == 1) ? cur
                  : (d == 2) ? RE + i2 * (WW-1) + j2 - 1 : RE + i2 * (WW-1) + j2;
            int o = (d == 0) ? cur - WW : (d == 1) ? cur + WW
                  : (d == 2) ? cur - 1 : cur + 1;
            int d2 = (int)((D0[o >> 4] >> ((o & 15) * 2)) & 3u);
            int i3 = o >> 8, j3 = o & 255;
            int e2 = (d2 == 0) ? o - WW : (d2 == 1) ? o
                   : (d2 == 2) ? RE + i3 * (WW-1) + j3 - 1 : RE + i3 * (WW-1) + j3;
            if (e2 == e) { lab[n] = (u16)((cur < o) ? cur : o); break; }
            cur = o; d = d2;
        }
    }
    __syncthreads();
    // ---- step 3: renumber roots -> compact ids (order-free), relabel
    for (int n = tid; n < NN; n += 1024) {
        bool isr = (lab[n] == (u16)n);
        u64 bal = __ballot(isr);
        u32 base2 = 0;
        if (lane == 0 && bal) base2 = (u32)atomicAdd(&cntc, (int)__popcll(bal));
        base2 = (u32)__shfl((int)base2, 0, 64);
        if (isr) W16[n] = (u16)(base2 + (u32)__popcll(bal & ((1ull << lane) - 1)));
    }
    __syncthreads();
    for (int n = tid; n < NN; n += 1024) lab[n] = W16[lab[n]];
    __syncthreads();
    int C = cntc;                    // C0 <= 16384 (mutual trees have >=2 nodes)

    // thread's edge k-bit <-> e = (k<<10)+tid ; k=63 invalid for tid>=640
    u64 dead = (tid >= (EE - 63 * 1024)) ? (1ull << 63) : 0ull;

    // ======== round 1: u32 two-pass (bestW then bestE), C <= 16384 ========
    if (C > 1) {
        for (int c = tid; c < C; c += 1024) W32[c] = ~0u;
        __syncthreads();
        u64 act = 0;
        { u64 m = ~dead;
          while (m) {
            int k = __ffsll((long long)m) - 1; m &= m - 1;
            int e = (k << 10) + tid; int u, v; edge_uv(e, u, v);
            u32 cu = lab[u], cv = lab[v];
            if (cu == cv) { dead |= 1ull << k; continue; }
            act |= 1ull << k;
            u32 wk = kb[e];
            atomicMin(&W32[cu], wk);
            atomicMin(&W32[cv], wk);
          } }
        __syncthreads();
        u64 mu = 0, mv = 0;
        { u64 mm = act;
          while (mm) {
            int k = __ffsll((long long)mm) - 1; mm &= mm - 1;
            int e = (k << 10) + tid; int u, v; edge_uv(e, u, v);
            u32 wk = kb[e];
            if (W32[lab[u]] == wk) mu |= 1ull << k;
            if (W32[lab[v]] == wk) mv |= 1ull << k;
          } }
        __syncthreads();
        for (int c = tid; c < C; c += 1024) W32[c] = ~0u;
        __syncthreads();
        { u64 mm = mu | mv;
          while (mm) {
            int k = __ffsll((long long)mm) - 1; mm &= mm - 1;
            int e = (k << 10) + tid; int u, v; edge_uv(e, u, v);
            if ((mu >> k) & 1) atomicMin(&W32[lab[u]], (u32)e);
            if ((mv >> k) & 1) atomicMin(&W32[lab[v]], (u32)e);
          } }
        __syncthreads();
        { u64 mm = mu | mv;
          while (mm) {
            int k = __ffsll((long long)mm) - 1; mm &= mm - 1;
            int e = (k << 10) + tid; int u, v; edge_uv(e, u, v);
            u32 cu = lab[u], cv = lab[v];
            bool wU = ((mu >> k) & 1) && (W32[cu] == (u32)e);   // tag kills stale match
            bool wV = ((mv >> k) & 1) && (W32[cv] == (u32)e);
            if (wU | wV) {
                atomicOr(&selw[e >> 5], 1u << (e & 31));
                if (wU && wV) { u32 mn = cu < cv ? cu : cv, mx = cu ^ cv ^ mn;
                                W32[mx] = TAG32 | mn; W32[mn] = TAG32 | mn; }
                else if (wU)  W32[cu] = TAG32 | cv;
                else          W32[cv] = TAG32 | cu;
            }
          } }
        if (tid == 0) cntc = 0;
        __syncthreads();
        for (int c = tid; c < C; c += 1024) {       // compress to roots
            u32 x = (u32)c, nx = W32[x] & 0x3FFFu;
            while (nx != x) { x = nx; nx = W32[x] & 0x3FFFu; }
            W32[c] = TAG32 | x;
        }
        __syncthreads();
        for (int c = tid; c < C; c += 1024) {       // renumber roots
            bool isr = ((W32[c] & 0x3FFFu) == (u32)c);
            u64 bal = __ballot(isr);
            u32 base2 = 0;
            if (lane == 0 && bal) base2 = (u32)atomicAdd(&cntc, (int)__popcll(bal));
            base2 = (u32)__shfl((int)base2, 0, 64);
            if (isr) W32[c] = TAG32 | (u32)c |
                              ((base2 + (u32)__popcll(bal & ((1ull << lane) - 1))) << 16);
        }
        __syncthreads();
        for (int n = tid; n < NN; n += 1024) {      // relabel nodes
            u32 r = W32[lab[n]] & 0x3FFFu;
            lab[n] = (u16)((W32[r] >> 16) & 0x1FFFu);
        }
        __syncthreads();
        C = cntc;                                   // C1 <= 8192
    }

    // ======== rounds 2..14: u64 single-pass, C <= 8192 ====================
    for (int r = 2; r < 15 && C > 1; ++r) {
        for (int c = tid; c < C; c += 1024) Wbuf[c] = ~0ull;
        __syncthreads();
        u64 act = 0;
        { u64 m = ~dead;
          while (m) {
            int k = __ffsll((long long)m) - 1; m &= m - 1;
            int e = (k << 10) + tid; int u, v; edge_uv(e, u, v);
            u32 cu = lab[u], cv = lab[v];
            if (cu == cv) { dead |= 1ull << k; continue; }
            act |= 1ull << k;
            u64 key = ((u64)kb[e] << 32) | (u32)(e + KOFF);
            atomicMin(&Wbuf[cu], key);
            atomicMin(&Wbuf[cv], key);
          } }
        __syncthreads();
        { u64 mm = act;
          while (mm) {
            int k = __ffsll((long long)mm) - 1; mm &= mm - 1;
            int e = (k << 10) + tid; int u, v; edge_uv(e, u, v);
            u32 cu = lab[u], cv = lab[v];
            u64 key = ((u64)kb[e] << 32) | (u32)(e + KOFF);
            bool wU = (Wbuf[cu] == key);            // tag/KOFF kill torn matches
            bool wV = (Wbuf[cv] == key);
            if (wU | wV) {
                atomicOr(&selw[e >> 5], 1u << (e & 31));
                if (wU && wV) { u32 mn = cu < cv ? cu : cv, mx = cu ^ cv ^ mn;
                                Wbuf[mx] = TAG64 | mn; Wbuf[mn] = TAG64 | mn; }
                else if (wU)  Wbuf[cu] = TAG64 | cv;
                else          Wbuf[cv] = TAG64 | cu;
            }
          } }
        if (tid == 0) cntc = 0;
        __syncthreads();
        for (int c = tid; c < C; c += 1024) {       // compress to roots
            u32 x = (u32)c, nx = (u32)Wbuf[x] & 0x1FFFu;
            while (nx != x) { x = nx; nx = (u32)Wbuf[x] & 0x1FFFu; }
            Wbuf[c] = TAG64 | x;
        }
        __syncthreads();
        for (int c = tid; c < C; c += 1024) {       // renumber roots
            bool isr = (((u32)Wbuf[c] & 0x1FFFu) == (u32)c);
            u64 bal = __ballot(isr);
            u32 base2 = 0;
            if (lane == 0 && bal) base2 = (u32)atomicAdd(&cntc, (int)__popcll(bal));
            base2 = (u32)__shfl((int)base2, 0, 64);
            if (isr) Wbuf[c] = TAG64 | (u32)c |
                               ((u64)(base2 + (u32)__popcll(bal & ((1ull << lane) - 1))) << 32);
        }
        __syncthreads();
        for (int n = tid; n < NN; n += 1024) {      // relabel nodes
            u32 rr = (u32)Wbuf[lab[n]] & 0x1FFFu;
            lab[n] = (u16)((u32)(Wbuf[rr] >> 32) & 0xFFFFu);
        }
        __syncthreads();
        C = cntc;
    }

    // ---- in-block stable compaction from LDS bitmask (thread owns 64 eids)
    u32 w0 = selw[tid * 2], w1 = selw[tid * 2 + 1];
    int cnt = __popc(w0) + __popc(w1);
    int wid = tid >> 6;
    int inc = cnt;
    #pragma unroll
    for (int d = 1; d < 64; d <<= 1) {
        int t2 = __shfl_up(inc, d, 64);
        if (lane >= d) inc += t2;
    }
    if (lane == 63) wsum[wid] = inc;
    __syncthreads();
    if (tid < 16) {
        int vv = wsum[tid];
        int inc2 = vv;
        #pragma unroll
        for (int d = 1; d < 16; d <<= 1) {
            int t2 = __shfl_up(inc2, d, 16);
            if (tid >= d) inc2 += t2;
        }
        wsum[tid] = inc2 - vv;                      // exclusive wave base
    }
    __syncthreads();
    int pos = wsum[wid] + inc - cnt;
    int* ob = out + (size_t)b * (NN - 1) * 2;
    u64 bits = ((u64)w1 << 32) | (u64)w0;
    while (bits) {
        int bi = __ffsll((long long)bits) - 1;
        bits &= bits - 1;
        int e = (tid << 6) + bi;
        int u, v; edge_uv(e, u, v);
        ob[(size_t)pos * 2] = u;
        ob[(size_t)pos * 2 + 1] = v;
        ++pos;
    }
}

extern "C" void kernel_launch(void* const* d_in, const int* in_sizes, int n_in,
                              void* d_out, int out_size, void* d_ws, size_t ws_size,
                              hipStream_t stream) {
    const float* g = (const float*)d_in[0];
    int* out = (int*)d_out;
    u32* keyw = (u32*)d_ws;                          // B*EPAD*4 = 1 MB

    k_keys<<<512, 256, 0, stream>>>(g, keyw);
    k_mst4<<<4, 1024, 0, stream>>>(keyw, out);
}